// Round 18
// baseline (311.786 us; speedup 1.0000x reference)
//
#include <hip/hip_runtime.h>
#include <hip/hip_bf16.h>
#include <math.h>

#define DIMD   1024
#define NBATCH 4
#define NSEQ   8192
#define NTOK   (NBATCH * NSEQ)
#define NHEAVY 1024
#define NSEL   (NBATCH * NHEAVY)
#define DLIGHT 512
#define DHEAVY 4096
#define NITERS 50
#define BK     64

typedef __attribute__((ext_vector_type(8))) short short8;
typedef __attribute__((ext_vector_type(4))) float f32x4;
typedef __attribute__((ext_vector_type(4))) unsigned short u16x4;

__device__ __forceinline__ unsigned short f2bf(float f) {
    __hip_bfloat16 h = __float2bfloat16(f);
    union { __hip_bfloat16 h; unsigned short u; } cvt;
    cvt.h = h;
    return cvt.u;
}

__device__ __forceinline__ float bf2f(unsigned short u) {
    return __uint_as_float((unsigned)u << 16);
}

// Abramowitz-Stegun 7.1.26 erf, |eps|<=1.5e-7, single path (no branches).
__device__ __forceinline__ float gelu_fast(float x) {
    float ax = fabsf(x) * 0.7071067811865475f;
    float t = 1.0f / fmaf(0.3275911f, ax, 1.0f);
    float p = fmaf(t, 1.061405429f, -1.453152027f);
    p = fmaf(t, p, 1.421413741f);
    p = fmaf(t, p, -0.284496736f);
    p = fmaf(t, p, 0.254829592f);
    p = p * t;
    float e = __expf(-ax * ax);
    float erf_abs = fmaf(-p, e, 1.0f);
    float erf = copysignf(erf_abs, x);
    return 0.5f * x * (1.0f + erf);
}

__device__ __forceinline__ void gload_lds16(const void* g, void* l) {
    __builtin_amdgcn_global_load_lds(
        (const __attribute__((address_space(1))) void*)g,
        (__attribute__((address_space(3))) void*)l,
        16, 0, 0);
}

// ===== fused init: 4x cvt_transpose + xpass (+inv=-1), 1-D block-range =====
__global__ __launch_bounds__(256) void fused_init(
    const float* __restrict__ lw1, const float* __restrict__ lw2,
    const float* __restrict__ hw1, const float* __restrict__ hw2,
    const float* __restrict__ lgamma, const float* __restrict__ hgamma,
    short* __restrict__ wl1t, short* __restrict__ wl2t,
    short* __restrict__ wh1t, short* __restrict__ wh2t,
    const float* __restrict__ x, const float* __restrict__ rt,
    unsigned short* __restrict__ xb, float* __restrict__ sc,
    double* __restrict__ s_out, int* __restrict__ inv) {
    __shared__ float tile[32][33];
    __shared__ float red[4];
    __shared__ double redd[4];
    int b = blockIdx.x;
    int tid = threadIdx.x;

    const float* cin = nullptr; short* cout = nullptr; const float* cg = nullptr;
    int cK = 0, cN = 0, cnx = 0, cb = 0;
    if (b < 512)        { cin = lw1; cout = wl1t; cg = lgamma; cK = DIMD;   cN = DLIGHT; cnx = 16;  cb = b; }
    else if (b < 1024)  { cin = lw2; cout = wl2t; cg = nullptr; cK = DLIGHT; cN = DIMD;  cnx = 32;  cb = b - 512; }
    else if (b < 5120)  { cin = hw1; cout = wh1t; cg = hgamma; cK = DIMD;   cN = DHEAVY; cnx = 128; cb = b - 1024; }
    else if (b < 9216)  { cin = hw2; cout = wh2t; cg = nullptr; cK = DHEAVY; cN = DIMD;  cnx = 32;  cb = b - 5120; }

    if (cin) {
        int n0 = (cb % cnx) * 32, k0 = (cb / cnx) * 32;
        int tx = tid & 31, ty = tid >> 5;  // (32, 8)
        #pragma unroll
        for (int j = 0; j < 4; j++) {
            int k = k0 + ty + 8 * j;
            float g = cg ? cg[k] : 1.0f;
            tile[ty + 8 * j][tx] = cin[(size_t)k * cN + (n0 + tx)] * g;
        }
        __syncthreads();
        #pragma unroll
        for (int j = 0; j < 4; j++)
            cout[(size_t)(n0 + ty + 8 * j) * cK + (k0 + tx)] =
                (short)f2bf(tile[tx][ty + 8 * j]);
        return;
    }

    int t = b - 9216;  // token id
    const float4* xr = (const float4*)(x + (size_t)t * DIMD);
    float4 v = xr[tid];
    ushort4 pk;
    pk.x = f2bf(v.x); pk.y = f2bf(v.y); pk.z = f2bf(v.z); pk.w = f2bf(v.w);
    ((ushort4*)(xb + (size_t)t * DIMD))[tid] = pk;

    float ss = v.x * v.x + v.y * v.y + v.z * v.z + v.w * v.w;
    float4 rv = ((const float4*)rt)[tid];
    double sd = (double)v.x * rv.x + (double)v.y * rv.y + (double)v.z * rv.z + (double)v.w * rv.w;
    #pragma unroll
    for (int off = 32; off > 0; off >>= 1) {
        ss += __shfl_down(ss, off);
        sd += __shfl_down(sd, off);
    }
    if ((tid & 63) == 0) { red[tid >> 6] = ss; redd[tid >> 6] = sd; }
    __syncthreads();
    if (tid == 0) {
        s_out[t] = redd[0] + redd[1] + redd[2] + redd[3];
        float tot = red[0] + red[1] + red[2] + red[3];
        sc[t] = 32.0f / fmaxf(sqrtf(tot), 1e-12f);
        inv[t] = -1;
    }
}

// ===== megakernel: blocks 0-3 = descent (exact 49-step map) THEN single-wave
// select; blocks 4.. = light GEMM1 (128x128, T2-swizzled, SINGLE-barrier
// T3-recipe loop). LDS = exactly 64 KB (redd aliases smem[0..64): dead before
// sw is written; GEMM blocks never touch it) -> 2 blocks/CU co-tenancy
// (r17: 66 KB allocation forced 1 block/CU = 11.7% occupancy, 4 serial rounds).
__global__ __launch_bounds__(256) void mega_kern(
    const double* __restrict__ s, int* __restrict__ sel, int* __restrict__ inv,
    const short* __restrict__ A, const short* __restrict__ Bt,
    const float* __restrict__ bias, const float* __restrict__ sc,
    __hip_bfloat16* __restrict__ outb) {
    __shared__ alignas(16) char smem[65536];  // exactly 64 KB
    short (*As)[128 * 64] = reinterpret_cast<short (*)[128 * 64]>(smem);
    short (*Bs)[128 * 64] = reinterpret_cast<short (*)[128 * 64]>(smem + 32768);
    int tid = threadIdx.x;

    if (blockIdx.x < 4) {
        // ---- descent: 256 threads / 4 waves, es[32]/lane, exact r12 map ----
        int r = blockIdx.x;
        int lw = tid & 63, w = tid >> 6;
        double* redd = (double*)smem;  // 8 doubles; aliases sw (dead by then)
        const double* sr = s + (size_t)r * NSEQ;
        double es[32];
        #pragma unroll
        for (int i = 0; i < 32; i++) es[i] = exp(sr[tid + i * 256]);
        const double Kk = 1152.0;  // min(1024 * 9/8, 8192)
        double ea = exp(log(Kk) - log((double)NSEQ));  // e^{a_1}
        for (int it = 1; it < NITERS; it++) {
            double loc = 0.0;
            #pragma unroll
            for (int i = 0; i < 32; i++) {
                double p = es[i] * ea;
                loc += (p < 1.0 ? p : 1.0);
            }
            #pragma unroll
            for (int off = 32; off > 0; off >>= 1) loc += __shfl_down(loc, off);
            int pb = (it & 1) * 4;
            if (lw == 0) redd[pb + w] = loc;
            __syncthreads();
            double S = redd[pb] + redd[pb + 1] + redd[pb + 2] + redd[pb + 3];
            ea = ea * (Kk / S);  // redundant per-thread; deterministic
        }
        double a = log(ea);
        __syncthreads();  // all redd reads done before sw overwrites smem
        if (tid >= 64) return;

        // ---- select: single wave, sw[] reuses the full 64 KB ----
        int l = tid;
        double* sw = (double*)smem;
        int cnt = 0;
        for (int base = 0; base < NSEQ; base += 64) {
            int idx = base + l;
            double v = sr[idx];
            bool sat = (v + a) >= 0.0;
            sw[idx] = sat ? -1.0e300 : v;
            unsigned long long m = __ballot(sat);
            int pre = __popcll(m & ((1ull << l) - 1ull));
            if (sat) {
                int slot = cnt + pre;
                if (slot < NHEAVY) {
                    sel[r * NHEAVY + slot] = r * NSEQ + idx;
                    inv[r * NSEQ + idx] = r * NHEAVY + slot;
                }
            }
            cnt += (int)__popcll(m);
        }
        for (int slot = cnt; slot < NHEAVY; slot++) {  // rarely taken fallback
            double best = -1.0e301; int bidx = NSEQ;
            for (int i = 0; i < NSEQ / 64; i++) {
                int idx = i * 64 + l;
                double v = sw[idx];
                if (v > best) { best = v; bidx = idx; }
            }
            #pragma unroll
            for (int off = 32; off > 0; off >>= 1) {
                double ov = __shfl_down(best, off);
                int oi = __shfl_down(bidx, off);
                if (ov > best || (ov == best && oi < bidx)) { best = ov; bidx = oi; }
            }
            bidx = __shfl(bidx, 0);
            if (l == 0) {
                sel[r * NHEAVY + slot] = r * NSEQ + bidx;
                inv[r * NSEQ + bidx] = r * NHEAVY + slot;
                sw[bidx] = -1.0e300;
            }
        }
        return;
    }

    // ---- light GEMM1: C[M=NTOK, N=DLIGHT] = xb * wl1t^T, gelu(sc*acc+b) ----
    const int N = DLIGHT, K = DIMD;
    int gid = blockIdx.x - 4;          // 0..1023
    int id = (gid & 7) * (1024 >> 3) + (gid >> 3);  // bijective XCD swizzle
    int nx = N / 128;                  // 4
    int bxi = id % nx, byi = id / nx;
    int l = tid & 63, w = tid >> 6;
    int wr = w >> 1, wc = w & 1;
    int bn0 = bxi * 128, bm0 = byi * 128;

    f32x4 zero = {0.f, 0.f, 0.f, 0.f};
    f32x4 acc[4][4];
    #pragma unroll
    for (int i = 0; i < 4; i++)
        #pragma unroll
        for (int j = 0; j < 4; j++) acc[i][j] = zero;

    // T2: pre-swizzled global staging sources (o = p ^ ((p>>7&7)<<4)).
    const short* AgC[4];
    const short* BgC[4];
    #pragma unroll
    for (int c = 0; c < 4; c++) {
        int p = c * 4096 + tid * 16;
        int o = p ^ (((p >> 7) & 7) << 4);
        int lrow = o >> 7, colb = o & 127;
        AgC[c] = A + (size_t)(bm0 + lrow) * K + (colb >> 1);
        BgC[c] = Bt + (size_t)(bn0 + lrow) * K + (colb >> 1);
    }
    const int sbase = (tid & ~63) * 8;  // wave-uniform LDS base (+lane*16B by HW)

    auto stage = [&](int b, int k0) {
        #pragma unroll
        for (int c = 0; c < 4; c++) {
            gload_lds16(AgC[c] + k0, &As[b][sbase + c * 2048]);
            gload_lds16(BgC[c] + k0, &Bs[b][sbase + c * 2048]);
        }
    };

    // swizzled ds_read columns: col_kk = ((l>>4)*16 + kk*64) ^ ((lr&7)<<4)
    const int lr16 = l & 15;
    const int swzm = (lr16 & 7) << 4;
    const int colkm[2] = { ((l >> 4) * 16) ^ swzm, (((l >> 4) * 16) + 64) ^ swzm };

    // T3-recipe minimum loop: ONE barrier + one vmcnt(0) per tile; no explicit
    // lgkm drains (compiler emits fine-grained lgkmcnt per MFMA — m97 mode).
    int nt = K / 64;  // 16
    stage(0, 0);
    asm volatile("s_waitcnt vmcnt(0)" ::: "memory");
    __builtin_amdgcn_s_barrier();
    for (int t = 0; t < nt; ++t) {
        int cur = t & 1;
        if (t + 1 < nt) stage(cur ^ 1, (t + 1) * 64);
        const char* aBuf = (const char*)&As[cur][0];
        const char* bBuf = (const char*)&Bs[cur][0];
        __builtin_amdgcn_s_setprio(1);
        #pragma unroll
        for (int kk = 0; kk < 2; kk++) {
            short8 af[4], bf[4];
            #pragma unroll
            for (int i = 0; i < 4; i++) {
                af[i] = *reinterpret_cast<const short8*>(aBuf + (wr * 64 + i * 16 + lr16) * 128 + colkm[kk]);
                bf[i] = *reinterpret_cast<const short8*>(bBuf + (wc * 64 + i * 16 + lr16) * 128 + colkm[kk]);
            }
            #pragma unroll
            for (int mi = 0; mi < 4; mi++)
                #pragma unroll
                for (int ni = 0; ni < 4; ni++)
                    acc[mi][ni] = __builtin_amdgcn_mfma_f32_16x16x32_bf16(bf[ni], af[mi], acc[mi][ni], 0, 0, 0);
        }
        __builtin_amdgcn_s_setprio(0);
        if (t + 1 < nt) {
            asm volatile("s_waitcnt vmcnt(0)" ::: "memory");  // next tile landed; fences LDS reads
            __builtin_amdgcn_s_barrier();                     // cross-wave: reads done + stage visible
        }
    }

    int orow0 = bm0 + wr * 64, ocol0 = bn0 + wc * 64;
    const int lq = (l >> 4) * 4;
    #pragma unroll
    for (int mi = 0; mi < 4; mi++) {
        int row = orow0 + mi * 16 + lr16;
        float scv = sc[row];
        #pragma unroll
        for (int ni = 0; ni < 4; ni++) {
            int c0 = ocol0 + ni * 16 + lq;
            f32x4 bv = *reinterpret_cast<const f32x4*>(bias + c0);
            u16x4 pk;
            #pragma unroll
            for (int rg = 0; rg < 4; rg++)
                pk[rg] = f2bf(gelu_fast(fmaf(scv, acc[mi][ni][rg], bv[rg])));
            *reinterpret_cast<u16x4*>((unsigned short*)outb + (size_t)row * N + c0) = pk;
        }
    }
}

// hv[h][c] = hb2[c] + sum_j phb[j][h][c]   (dense heavy-output reduce, f32)
__global__ __launch_bounds__(256) void reduce_hv_kern(
    const unsigned short* __restrict__ phb, const float* __restrict__ hb2,
    float* __restrict__ hv, int nsk) {
    int h = blockIdx.x;          // 0..NSEL-1
    int c0 = threadIdx.x * 4;    // 256 threads x 4 cols
    f32x4 acc = *reinterpret_cast<const f32x4*>(hb2 + c0);
    for (int j = 0; j < nsk; j++) {
        u16x4 p = *reinterpret_cast<const u16x4*>(phb + ((size_t)j * NSEL + h) * DIMD + c0);
        #pragma unroll
        for (int rg = 0; rg < 4; rg++) acc[rg] += bf2f(p[rg]);
    }
    *reinterpret_cast<f32x4*>(hv + (size_t)h * DIMD + c0) = acc;
}

// ===== 256x256 GEMM, SINGLE-barrier T3-recipe K-loop =====
// Per tile: stage(t+1 -> other buffer, 8 gloads) || ds_reads+MFMA (compiler
// fine-grained lgkm) -> vmcnt(0) (lands prefetch, fences LDS reads) -> ONE
// s_barrier. WAR ledger: iter-t reads retire before its barrier (lgkm before
// MFMA); iter-t+1 overwrites only after that barrier. r16 showed per-tile
// barrier/drain count is the tax (4->2 phases = -49us); this removes 1 more
// barrier + 2 lgkm drains per tile (catalog T3-minimum: m230 682 TF @128sq).
// T2 swizzle (pre-swizzled global src + swizzled ds_read, kk*64 inside XOR).
// EPI 0: bf16 out = gelu(sc_row*acc + bias)      (GEMM1s; sc via sel if GATHER)
// EPI 2: bf16 partial[bz][m][n] = acc            (heavy GEMM2 split-K)
// EPI 3: f32 out(NT) = acc + bias [+ hv[inv[row]]]  (light GEMM2 fused)
template <int EPI, bool GATHER>
__global__ __launch_bounds__(512) void gemm256(
    const short* __restrict__ A, const short* __restrict__ Bt,
    const float* __restrict__ bias,
    const float* __restrict__ sc, const int* __restrict__ sel,
    const int* __restrict__ inv, const float* __restrict__ hv,
    float* __restrict__ outf, __hip_bfloat16* __restrict__ outb,
    int M, int N, int K) {
    __shared__ alignas(16) short As[2][2][128 * 64];  // [dbuf][half] 16 KB each
    __shared__ alignas(16) short Bs[2][2][128 * 64];

    int nx = gridDim.x, ny = gridDim.y;
    int nwg = nx * ny * gridDim.z;
    int id = ((int)blockIdx.z * ny + blockIdx.y) * nx + blockIdx.x;
    if ((nwg & 7) == 0) id = (id & 7) * (nwg >> 3) + (id >> 3);
    int bxi = id % nx; int rem = id / nx;
    int byi = rem % ny; int bz = rem / ny;
    int klen = K / (int)gridDim.z, k0base = bz * klen;
    int bn0 = bxi * 256, bm0 = byi * 256;

    int tid = threadIdx.x;
    int l = tid & 63, w = tid >> 6;   // 8 waves
    int wr = w >> 2, wc = w & 3;      // 2 x 4

    f32x4 zero = {0.f, 0.f, 0.f, 0.f};
    f32x4 acc[8][4];
    #pragma unroll
    for (int i = 0; i < 8; i++)
        #pragma unroll
        for (int j = 0; j < 4; j++) acc[i][j] = zero;

    // pre-swizzled global staging sources (o = p ^ ((p>>7&7)<<4), involution)
    const short* aSrc[2][2];
    const short* bSrc[2][2];
    #pragma unroll
    for (int h = 0; h < 2; h++)
        #pragma unroll
        for (int j = 0; j < 2; j++) {
            int p = j * 8192 + tid * 16;
            int o = p ^ (((p >> 7) & 7) << 4);
            int lrow = o >> 7, colb = o & 127;
            int agrow = bm0 + h * 128 + lrow;
            int garow = GATHER ? sel[agrow] : agrow;
            aSrc[h][j] = A + (size_t)garow * K + (colb >> 1);
            bSrc[h][j] = Bt + (size_t)(bn0 + h * 128 + lrow) * K + (colb >> 1);
        }

    auto stageAll = [&](int b, int kof) {
        #pragma unroll
        for (int j = 0; j < 2; j++) gload_lds16(aSrc[0][j] + kof, &As[b][0][j * 4096 + w * 512]);
        #pragma unroll
        for (int j = 0; j < 2; j++) gload_lds16(aSrc[1][j] + kof, &As[b][1][j * 4096 + w * 512]);
        #pragma unroll
        for (int j = 0; j < 2; j++) gload_lds16(bSrc[0][j] + kof, &Bs[b][0][j * 4096 + w * 512]);
        #pragma unroll
        for (int j = 0; j < 2; j++) gload_lds16(bSrc[1][j] + kof, &Bs[b][1][j * 4096 + w * 512]);
    };

    int nt = klen / BK;
    stageAll(0, k0base);
    asm volatile("s_waitcnt vmcnt(0)" ::: "memory");
    __builtin_amdgcn_s_barrier();

    // swizzled ds_read columns: col_kk = ((l>>4)*16 + kk*64) ^ ((lr&7)<<4)
    const int lr = l & 15;
    const int swz = (lr & 7) << 4;
    const int rbase = lr * 128;
    const int colk[2] = { (((l >> 4) * 16)) ^ swz, (((l >> 4) * 16) + 64) ^ swz };

    for (int t = 0; t < nt; ++t) {
        int d = t & 1;
        if (t + 1 < nt) stageAll(d ^ 1, k0base + (t + 1) * BK);
        const char* aHalf = (const char*)(&As[d][wr][0]);
        const char* bHalf = (const char*)(&Bs[d][wc >> 1][0]) + (wc & 1) * 8192;
        short8 bfr[4][2];
        #pragma unroll
        for (int ni = 0; ni < 4; ni++)
            #pragma unroll
            for (int kk = 0; kk < 2; kk++)
                bfr[ni][kk] = *reinterpret_cast<const short8*>(bHalf + rbase + ni * 2048 + colk[kk]);
        #pragma unroll
        for (int ph = 0; ph < 2; ph++) {
            short8 afr[4][2];
            #pragma unroll
            for (int m2 = 0; m2 < 4; m2++)
                #pragma unroll
                for (int kk = 0; kk < 2; kk++)
                    afr[m2][kk] = *reinterpret_cast<const short8*>(aHalf + rbase + (ph * 4 + m2) * 2048 + colk[kk]);
            __builtin_amdgcn_s_setprio(1);
            #pragma unroll
            for (int m2 = 0; m2 < 4; m2++)
                #pragma unroll
                for (int ni = 0; ni < 4; ni++)
                    #pragma unroll
                    for (int kk = 0; kk < 2; kk++)
                        acc[ph * 4 + m2][ni] = __builtin_amdgcn_mfma_f32_16x16x32_bf16(
                            bfr[ni][kk], afr[m2][kk], acc[ph * 4 + m2][ni], 0, 0, 0);
            __builtin_amdgcn_s_setprio(0);
        }
        if (t + 1 < nt) {
            asm volatile("s_waitcnt vmcnt(0)" ::: "memory");  // prefetch landed; fences LDS reads
            __builtin_amdgcn_s_barrier();
        }
    }

    // Swapped-D: row = bm0 + wr*128 + mi*16 + (l&15); cols = bn0 + wc*64 + ni*16 + (l>>4)*4 + reg
    int orow0 = bm0 + wr * 128, ocol0 = bn0 + wc * 64;
    const int lq = (l >> 4) * 4;
    #pragma unroll
    for (int mi = 0; mi < 8; mi++) {
        int row = orow0 + mi * 16 + lr;
        float scv = 0.0f;
        int iv = -1;
        if (EPI == 0) scv = sc[GATHER ? sel[row] : row];
        if (EPI == 3) iv = inv[row];
        #pragma unroll
        for (int ni = 0; ni < 4; ni++) {
            int c0 = ocol0 + ni * 16 + lq;
            if (EPI == 0) {
                f32x4 bv = *reinterpret_cast<const f32x4*>(bias + c0);
                u16x4 pk;
                #pragma unroll
                for (int rg = 0; rg < 4; rg++)
                    pk[rg] = f2bf(gelu_fast(fmaf(scv, acc[mi][ni][rg], bv[rg])));
                *reinterpret_cast<u16x4*>((unsigned short*)outb + (size_t)row * N + c0) = pk;
            } else if (EPI == 2) {
                u16x4 pk;
                #pragma unroll
                for (int rg = 0; rg < 4; rg++) pk[rg] = f2bf(acc[mi][ni][rg]);
                *reinterpret_cast<u16x4*>((unsigned short*)outb + ((size_t)bz * M + row) * (size_t)N + c0) = pk;
            } else {  // EPI == 3
                f32x4 bv = *reinterpret_cast<const f32x4*>(bias + c0);
                f32x4 v = acc[mi][ni] + bv;
                if (iv >= 0) {
                    f32x4 hvv = *reinterpret_cast<const f32x4*>(hv + (size_t)iv * DIMD + c0);
                    v = v + hvv;
                }
                __builtin_nontemporal_store(v, reinterpret_cast<f32x4*>(outf + (size_t)row * N + c0));
            }
        }
    }
}

extern "C" void kernel_launch(void* const* d_in, const int* in_sizes, int n_in,
                              void* d_out, int out_size, void* d_ws, size_t ws_size,
                              hipStream_t stream) {
    (void)in_sizes; (void)n_in; (void)out_size;
    const float* x      = (const float*)d_in[0];
    const float* rt     = (const float*)d_in[1];
    const float* lgamma = (const float*)d_in[2];
    const float* lw1    = (const float*)d_in[3];
    const float* lb1    = (const float*)d_in[4];
    const float* lw2    = (const float*)d_in[5];
    const float* lb2    = (const float*)d_in[6];
    const float* hgamma = (const float*)d_in[7];
    const float* hw1    = (const float*)d_in[8];
    const float* hb1    = (const float*)d_in[9];
    const float* hw2    = (const float*)d_in[10];
    const float* hb2    = (const float*)d_in[11];
    float* out = (float*)d_out;

    auto rnd = [](size_t b) { return (b + 255) & ~(size_t)255; };
    size_t fixed = rnd(NTOK * sizeof(double))        // s
                 + rnd(NSEL * sizeof(int))           // sel
                 + rnd(NTOK * sizeof(int))           // inv
                 + rnd(NTOK * sizeof(float))         // sc
                 + rnd((size_t)DLIGHT * DIMD * 2)    // wl1t
                 + rnd((size_t)DIMD * DLIGHT * 2)    // wl2t
                 + rnd((size_t)DHEAVY * DIMD * 2)    // wh1t
                 + rnd((size_t)DIMD * DHEAVY * 2)    // wh2t
                 + rnd((size_t)NTOK * DIMD * 2)      // xb
                 + rnd((size_t)NSEL * DHEAVY * 2)    // hh
                 + rnd((size_t)NTOK * DLIGHT * 2)    // hl
                 + rnd((size_t)NSEL * DIMD * 4);     // hv (f32)
    int nsk = 4;
    while (nsk > 1 && fixed + rnd((size_t)nsk * NSEL * DIMD * 2) > ws_size) nsk >>= 1;

    char* base = (char*)d_ws;
    size_t off = 0;
    auto alloc = [&](size_t bytes) -> void* {
        void* p = base + off;
        off += rnd(bytes);
        return p;
    };
    double* s     = (double*)alloc(NTOK * sizeof(double));
    int*    sel   = (int*)alloc(NSEL * sizeof(int));
    int*    inv   = (int*)alloc(NTOK * sizeof(int));
    float*  sc    = (float*)alloc(NTOK * sizeof(float));
    short*  wl1t  = (short*)alloc((size_t)DLIGHT * DIMD * 2);
    short*  wl2t  = (short*)alloc((size_t)DIMD * DLIGHT * 2);
    short*  wh1t  = (short*)alloc((size_t)DHEAVY * DIMD * 2);
    short*  wh2t  = (short*)alloc((size_t)DIMD * DHEAVY * 2);
    short*  xb    = (short*)alloc((size_t)NTOK * DIMD * 2);
    short*  hh    = (short*)alloc((size_t)NSEL * DHEAVY * 2);
    short*  hl    = (short*)alloc((size_t)NTOK * DLIGHT * 2);
    float*  hv    = (float*)alloc((size_t)NSEL * DIMD * 4);
    short*  phb   = (short*)alloc((size_t)nsk * NSEL * DIMD * 2);

    // fused init: 4x weight cvt_transpose (gamma folded into W1) + xpass + inv=-1
    fused_init<<<9216 + NTOK, 256, 0, stream>>>(
        lw1, lw2, hw1, hw2, lgamma, hgamma,
        wl1t, wl2t, wh1t, wh2t,
        x, rt, (unsigned short*)xb, sc, s, inv);

    // megakernel: descent+select (blocks 0-3) || light GEMM1 (blocks 4-1027)
    mega_kern<<<4 + 1024, 256, 0, stream>>>(
        s, sel, inv, xb, wl1t, lb1, sc, (__hip_bfloat16*)hl);

    // heavy: GEMM1 (gather rows of xb, sc+gelu epi) -> hh; GEMM2 split-K -> phb; reduce -> hv
    gemm256<0, true><<<dim3(DHEAVY / 256, NSEL / 256), 512, 0, stream>>>(
        xb, wh1t, hb1, sc, sel, nullptr, nullptr,
        nullptr, (__hip_bfloat16*)hh, NSEL, DHEAVY, DIMD);
    gemm256<2, false><<<dim3(DIMD / 256, NSEL / 256, nsk), 512, 0, stream>>>(
        hh, wh2t, nullptr, nullptr, nullptr, nullptr, nullptr,
        nullptr, (__hip_bfloat16*)phb, NSEL, DIMD, DHEAVY);
    reduce_hv_kern<<<NSEL, 256, 0, stream>>>((const unsigned short*)phb, hb2, hv, nsk);

    // light GEMM2 fused (+hv via inv) -> out
    gemm256<3, false><<<dim3(DIMD / 256, NTOK / 256), 512, 0, stream>>>(
        hl, wl2t, lb2, nullptr, nullptr, inv, hv,
        out, nullptr, NTOK, DIMD, DLIGHT);
}